// Round 1
// baseline (5145.054 us; speedup 1.0000x reference)
//
#include <hip/hip_runtime.h>

// Problem constants (from reference)
constexpr int Bb  = 16;    // batch
constexpr int Dd  = 128;   // latent dim
constexpr int Tt  = 2048;  // timesteps
constexpr int NQn = 8;     // num quantizers
constexpr int CSc = 1024;  // codebook size

constexpr int WAVES = 4;           // waves per block (split codebook scan)
constexpr int CPW   = CSc / WAVES; // codes per wave = 256

// ---------------------------------------------------------------------------
// Kernel 0: precompute ||c||^2 for all NQ*CS codes into d_ws
// ---------------------------------------------------------------------------
__global__ __launch_bounds__(64) void cnorm_kernel(const float* __restrict__ cb,
                                                   float* __restrict__ cnorm) {
    int c = blockIdx.x * 64 + threadIdx.x;   // 0 .. NQ*CS-1
    const float4* p = reinterpret_cast<const float4*>(cb + (size_t)c * Dd);
    float s0 = 0.f, s1 = 0.f, s2 = 0.f, s3 = 0.f;
#pragma unroll
    for (int k = 0; k < Dd / 4; ++k) {
        float4 v = p[k];
        s0 = fmaf(v.x, v.x, s0);
        s1 = fmaf(v.y, v.y, s1);
        s2 = fmaf(v.z, v.z, s2);
        s3 = fmaf(v.w, v.w, s3);
    }
    cnorm[c] = (s0 + s1) + (s2 + s3);
}

// ---------------------------------------------------------------------------
// Kernel 1: main RVQ. One lane owns one (b,t) vector; r[128] lives in VGPRs.
// 4 waves/block scan disjoint quarters of the codebook; argmin combined in LDS.
// q_sum = x0 - r_final (telescoping). loss partial per block -> d_ws.
// ---------------------------------------------------------------------------
__global__ __launch_bounds__(256) void rvq_kernel(const float* __restrict__ x,
                                                  const float* __restrict__ cb,
                                                  const float* __restrict__ cnorm,
                                                  float* __restrict__ out,
                                                  float* __restrict__ loss_part) {
    const int tid  = threadIdx.x;
    const int lane = tid & 63;
    // force wave id wave-uniform so codebook scan addresses scalarize (s_load)
    const int wave = __builtin_amdgcn_readfirstlane(tid >> 6);

    const int v = blockIdx.x * 64 + lane;  // global vector id in [0, B*T)
    const int b = v >> 11;                 // v / T   (T = 2048)
    const int t = v & (Tt - 1);            // v % T

    const float* xp = x + (size_t)b * Dd * Tt + t;

    // residual in registers (static indexing only)
    float r[Dd];
#pragma unroll
    for (int d = 0; d < Dd; ++d) r[d] = xp[(size_t)d * Tt];

    __shared__ float s_best[WAVES][64];
    __shared__ int   s_idx[WAVES][64];

    float loss_acc = 0.f;

    for (int q = 0; q < NQn; ++q) {
        // ||r||^2 (tree accumulation)
        float rn0 = 0.f, rn1 = 0.f, rn2 = 0.f, rn3 = 0.f;
#pragma unroll
        for (int d = 0; d < Dd; d += 4) {
            rn0 = fmaf(r[d + 0], r[d + 0], rn0);
            rn1 = fmaf(r[d + 1], r[d + 1], rn1);
            rn2 = fmaf(r[d + 2], r[d + 2], rn2);
            rn3 = fmaf(r[d + 3], r[d + 3], rn3);
        }
        const float rn = (rn0 + rn1) + (rn2 + rn3);

        const float* cbase = cb + ((size_t)q * CSc + (size_t)wave * CPW) * Dd;
        const float* cnb   = cnorm + q * CSc + wave * CPW;

        float best = 3.4e38f;
        int   bidx = 0;

        // scan 256 codes, 2 at a time (8 independent FMA chains for ILP)
        for (int c = 0; c < CPW; c += 2) {
            const float* cp0 = cbase + (size_t)c * Dd;
            const float* cp1 = cp0 + Dd;
            float a0 = 0.f, a1 = 0.f, a2 = 0.f, a3 = 0.f;
            float e0 = 0.f, e1 = 0.f, e2 = 0.f, e3 = 0.f;
#pragma unroll
            for (int d = 0; d < Dd; d += 4) {
                a0 = fmaf(cp0[d + 0], r[d + 0], a0);
                a1 = fmaf(cp0[d + 1], r[d + 1], a1);
                a2 = fmaf(cp0[d + 2], r[d + 2], a2);
                a3 = fmaf(cp0[d + 3], r[d + 3], a3);
                e0 = fmaf(cp1[d + 0], r[d + 0], e0);
                e1 = fmaf(cp1[d + 1], r[d + 1], e1);
                e2 = fmaf(cp1[d + 2], r[d + 2], e2);
                e3 = fmaf(cp1[d + 3], r[d + 3], e3);
            }
            float dot0 = (a0 + a1) + (a2 + a3);
            float dot1 = (e0 + e1) + (e2 + e3);
            // reference formula: d = ||r||^2 - 2 r.c + ||c||^2
            float dist0 = fmaf(-2.f, dot0, rn + cnb[c + 0]);
            float dist1 = fmaf(-2.f, dot1, rn + cnb[c + 1]);
            // strict < : first (lowest) index wins ties, ascending scan order
            if (dist0 < best) { best = dist0; bidx = c + 0; }
            if (dist1 < best) { best = dist1; bidx = c + 1; }
        }

        s_best[wave][lane] = best;
        s_idx[wave][lane]  = wave * CPW + bidx;
        __syncthreads();

        // combine across the 4 waves, ascending wave order (= ascending code idx)
        float gbest = s_best[0][lane];
        int   gidx  = s_idx[0][lane];
#pragma unroll
        for (int w = 1; w < WAVES; ++w) {
            float bw = s_best[w][lane];
            int   iw = s_idx[w][lane];
            if (bw < gbest) { gbest = bw; gidx = iw; }
        }
        __syncthreads();  // protect LDS reuse next stage

        // update residual with selected code; accumulate loss = ||r_new||^2
        const float4* cw4 =
            reinterpret_cast<const float4*>(cb + ((size_t)q * CSc + gidx) * Dd);
        float l0 = 0.f, l1 = 0.f, l2 = 0.f, l3 = 0.f;
#pragma unroll
        for (int k = 0; k < Dd / 4; ++k) {
            float4 cv = cw4[k];
            float w0 = r[4 * k + 0] - cv.x;
            float w1 = r[4 * k + 1] - cv.y;
            float w2 = r[4 * k + 2] - cv.z;
            float w3 = r[4 * k + 3] - cv.w;
            r[4 * k + 0] = w0;
            r[4 * k + 1] = w1;
            r[4 * k + 2] = w2;
            r[4 * k + 3] = w3;
            l0 = fmaf(w0, w0, l0);
            l1 = fmaf(w1, w1, l1);
            l2 = fmaf(w2, w2, l2);
            l3 = fmaf(w3, w3, l3);
        }
        loss_acc += (l0 + l1) + (l2 + l3);
    }

    // Epilogue: q_sum = x0 - r_final (wave 0 writes; all waves hold identical r)
    if (wave == 0) {
        float* op = out + (size_t)b * Dd * Tt + t;
#pragma unroll
        for (int d = 0; d < Dd; ++d)
            op[(size_t)d * Tt] = xp[(size_t)d * Tt] - r[d];

        // reduce loss across the 64 lanes of wave 0 (deterministic)
        float ls = loss_acc;
#pragma unroll
        for (int off = 32; off > 0; off >>= 1) ls += __shfl_down(ls, off, 64);
        if (lane == 0) loss_part[blockIdx.x] = ls;
    }
}

// ---------------------------------------------------------------------------
// Kernel 2: deterministic loss reduction: 32 block-partials per batch element
// ---------------------------------------------------------------------------
__global__ __launch_bounds__(64) void loss_kernel(const float* __restrict__ part,
                                                  float* __restrict__ out_loss) {
    int b = threadIdx.x;
    if (b < Bb) {
        float s = 0.f;
        const int ppb = Tt / 64;  // 32 partials per batch element
        for (int k = 0; k < ppb; ++k) s += part[b * ppb + k];
        out_loss[b] = s * (1.0f / ((float)Dd * (float)Tt));
    }
}

// ---------------------------------------------------------------------------
extern "C" void kernel_launch(void* const* d_in, const int* in_sizes, int n_in,
                              void* d_out, int out_size, void* d_ws, size_t ws_size,
                              hipStream_t stream) {
    const float* x  = (const float*)d_in[0];   // [B, D, T]
    const float* cb = (const float*)d_in[1];   // [NQ, CS, D]
    float* out = (float*)d_out;                // [B*D*T] q_sum ++ [B] loss_sum

    // workspace layout: cnorm[NQ*CS] then loss partials[B*T/64]
    float* cnorm = (float*)d_ws;
    float* part  = cnorm + NQn * CSc;

    cnorm_kernel<<<(NQn * CSc) / 64, 64, 0, stream>>>(cb, cnorm);

    const int nblocks = (Bb * Tt) / 64;  // 512
    rvq_kernel<<<nblocks, WAVES * 64, 0, stream>>>(x, cb, cnorm, out, part);

    loss_kernel<<<1, 64, 0, stream>>>(part, out + (size_t)Bb * Dd * Tt);
}

// Round 3
// 4467.112 us; speedup vs baseline: 1.1518x; 1.1518x over previous
//
#include <hip/hip_runtime.h>

// Problem constants (from reference)
constexpr int Bb  = 16;    // batch
constexpr int Dd  = 128;   // latent dim
constexpr int Tt  = 2048;  // timesteps
constexpr int NQn = 8;     // num quantizers
constexpr int CSc = 1024;  // codebook size

constexpr int WAVES = 4;           // waves per block (split codebook scan)
constexpr int CPW   = CSc / WAVES; // codes per wave = 256

// constant address space (4): uniform loads select s_load_dwordxN, and the
// compiler owns lgkmcnt/phi correctness (round-2's inline-asm version didn't).
using cfloat = const __attribute__((address_space(4))) float;

// ---------------------------------------------------------------------------
// Kernel 0: precompute ||c||^2 for all NQ*CS codes into d_ws
// ---------------------------------------------------------------------------
__global__ __launch_bounds__(64) void cnorm_kernel(const float* __restrict__ cb,
                                                   float* __restrict__ cnorm) {
    int c = blockIdx.x * 64 + threadIdx.x;   // 0 .. NQ*CS-1
    const float4* p = reinterpret_cast<const float4*>(cb + (size_t)c * Dd);
    float s0 = 0.f, s1 = 0.f, s2 = 0.f, s3 = 0.f;
#pragma unroll
    for (int k = 0; k < Dd / 4; ++k) {
        float4 v = p[k];
        s0 = fmaf(v.x, v.x, s0);
        s1 = fmaf(v.y, v.y, s1);
        s2 = fmaf(v.z, v.z, s2);
        s3 = fmaf(v.w, v.w, s3);
    }
    cnorm[c] = (s0 + s1) + (s2 + s3);
}

// ---------------------------------------------------------------------------
// Kernel 1: main RVQ. Lane = one (b,t) vector, r[128] in VGPRs.
// Codebook scanned through the scalar pipe (AS4 uniform loads -> s_load),
// v_fma_f32 consumes the code element as its single allowed SGPR operand.
// ---------------------------------------------------------------------------
__global__ __launch_bounds__(256) void rvq_kernel(const float* __restrict__ x,
                                                  const float* __restrict__ cb,
                                                  const float* __restrict__ cnorm,
                                                  float* __restrict__ out,
                                                  float* __restrict__ loss_part) {
    const int tid  = threadIdx.x;
    const int lane = tid & 63;
    // wave id made uniform so all codebook scan addresses are scalar
    const int wave = __builtin_amdgcn_readfirstlane(tid >> 6);

    const int v = blockIdx.x * 64 + lane;  // global vector id in [0, B*T)
    const int b = v >> 11;                 // v / T   (T = 2048)
    const int t = v & (Tt - 1);            // v % T

    const float* xp = x + (size_t)b * Dd * Tt + t;

    // residual in registers (static indexing only)
    float r[Dd];
#pragma unroll
    for (int d = 0; d < Dd; ++d) r[d] = xp[(size_t)d * Tt];

    __shared__ float s_best[WAVES][64];
    __shared__ int   s_idx[WAVES][64];

    float loss_acc = 0.f;

    for (int q = 0; q < NQn; ++q) {
        // ||r||^2 (tree accumulation)
        float rn0 = 0.f, rn1 = 0.f, rn2 = 0.f, rn3 = 0.f;
#pragma unroll
        for (int d = 0; d < Dd; d += 4) {
            rn0 = fmaf(r[d + 0], r[d + 0], rn0);
            rn1 = fmaf(r[d + 1], r[d + 1], rn1);
            rn2 = fmaf(r[d + 2], r[d + 2], rn2);
            rn3 = fmaf(r[d + 3], r[d + 3], rn3);
        }
        const float rn = (rn0 + rn1) + (rn2 + rn3);

        // uniform scan pointers through the constant (scalar) path
        cfloat* cbase = (cfloat*)(cb + ((size_t)q * CSc + (size_t)wave * CPW) * Dd);
        cfloat* cnb   = (cfloat*)(cnorm + q * CSc + wave * CPW);

        float best = 3.4e38f;
        int   bidx = 0;

        // scan 256 codes, 2 at a time (8 independent FMA chains for ILP)
        for (int c = 0; c < CPW; c += 2) {
            cfloat* cp0 = cbase + (size_t)c * Dd;
            cfloat* cp1 = cp0 + Dd;
            float a0 = 0.f, a1 = 0.f, a2 = 0.f, a3 = 0.f;
            float e0 = 0.f, e1 = 0.f, e2 = 0.f, e3 = 0.f;
#pragma unroll
            for (int d = 0; d < Dd; d += 4) {
                a0 = fmaf(cp0[d + 0], r[d + 0], a0);
                a1 = fmaf(cp0[d + 1], r[d + 1], a1);
                a2 = fmaf(cp0[d + 2], r[d + 2], a2);
                a3 = fmaf(cp0[d + 3], r[d + 3], a3);
                e0 = fmaf(cp1[d + 0], r[d + 0], e0);
                e1 = fmaf(cp1[d + 1], r[d + 1], e1);
                e2 = fmaf(cp1[d + 2], r[d + 2], e2);
                e3 = fmaf(cp1[d + 3], r[d + 3], e3);
            }
            float dot0 = (a0 + a1) + (a2 + a3);
            float dot1 = (e0 + e1) + (e2 + e3);
            // reference formula: d = ||r||^2 - 2 r.c + ||c||^2
            float dist0 = fmaf(-2.f, dot0, rn + cnb[c + 0]);
            float dist1 = fmaf(-2.f, dot1, rn + cnb[c + 1]);
            // strict < : first (lowest) index wins ties, ascending scan order
            if (dist0 < best) { best = dist0; bidx = c + 0; }
            if (dist1 < best) { best = dist1; bidx = c + 1; }
        }

        s_best[wave][lane] = best;
        s_idx[wave][lane]  = wave * CPW + bidx;
        __syncthreads();

        // combine across the 4 waves, ascending wave order (= ascending code idx)
        float gbest = s_best[0][lane];
        int   gidx  = s_idx[0][lane];
#pragma unroll
        for (int w = 1; w < WAVES; ++w) {
            float bw = s_best[w][lane];
            int   iw = s_idx[w][lane];
            if (bw < gbest) { gbest = bw; gidx = iw; }
        }
        __syncthreads();  // protect LDS reuse next stage

        // update residual with selected code; accumulate loss = ||r_new||^2
        // (gidx is per-lane divergent -> per-lane vector gather, as in round 1)
        const float4* cw4 =
            reinterpret_cast<const float4*>(cb + ((size_t)q * CSc + gidx) * Dd);
        float l0 = 0.f, l1 = 0.f, l2 = 0.f, l3 = 0.f;
#pragma unroll
        for (int k = 0; k < Dd / 4; ++k) {
            float4 cv = cw4[k];
            float w0 = r[4 * k + 0] - cv.x;
            float w1 = r[4 * k + 1] - cv.y;
            float w2 = r[4 * k + 2] - cv.z;
            float w3 = r[4 * k + 3] - cv.w;
            r[4 * k + 0] = w0;
            r[4 * k + 1] = w1;
            r[4 * k + 2] = w2;
            r[4 * k + 3] = w3;
            l0 = fmaf(w0, w0, l0);
            l1 = fmaf(w1, w1, l1);
            l2 = fmaf(w2, w2, l2);
            l3 = fmaf(w3, w3, l3);
        }
        loss_acc += (l0 + l1) + (l2 + l3);
    }

    // Epilogue: q_sum = x0 - r_final (wave 0 writes; all waves hold identical r)
    if (wave == 0) {
        float* op = out + (size_t)b * Dd * Tt + t;
#pragma unroll
        for (int d = 0; d < Dd; ++d)
            op[(size_t)d * Tt] = xp[(size_t)d * Tt] - r[d];

        // reduce loss across the 64 lanes of wave 0 (deterministic)
        float ls = loss_acc;
#pragma unroll
        for (int off = 32; off > 0; off >>= 1) ls += __shfl_down(ls, off, 64);
        if (lane == 0) loss_part[blockIdx.x] = ls;
    }
}

// ---------------------------------------------------------------------------
// Kernel 2: deterministic loss reduction: 32 block-partials per batch element
// ---------------------------------------------------------------------------
__global__ __launch_bounds__(64) void loss_kernel(const float* __restrict__ part,
                                                  float* __restrict__ out_loss) {
    int b = threadIdx.x;
    if (b < Bb) {
        float s = 0.f;
        const int ppb = Tt / 64;  // 32 partials per batch element
        for (int k = 0; k < ppb; ++k) s += part[b * ppb + k];
        out_loss[b] = s * (1.0f / ((float)Dd * (float)Tt));
    }
}

// ---------------------------------------------------------------------------
extern "C" void kernel_launch(void* const* d_in, const int* in_sizes, int n_in,
                              void* d_out, int out_size, void* d_ws, size_t ws_size,
                              hipStream_t stream) {
    const float* x  = (const float*)d_in[0];   // [B, D, T]
    const float* cb = (const float*)d_in[1];   // [NQ, CS, D]
    float* out = (float*)d_out;                // [B*D*T] q_sum ++ [B] loss_sum

    // workspace layout: cnorm[NQ*CS] then loss partials[B*T/64]
    float* cnorm = (float*)d_ws;
    float* part  = cnorm + NQn * CSc;

    cnorm_kernel<<<(NQn * CSc) / 64, 64, 0, stream>>>(cb, cnorm);

    const int nblocks = (Bb * Tt) / 64;  // 512
    rvq_kernel<<<nblocks, WAVES * 64, 0, stream>>>(x, cb, cnorm, out, part);

    loss_kernel<<<1, 64, 0, stream>>>(part, out + (size_t)Bb * Dd * Tt);
}

// Round 4
// 1842.816 us; speedup vs baseline: 2.7920x; 2.4241x over previous
//
#include <hip/hip_runtime.h>

// Problem constants (from reference)
constexpr int Bb  = 16;    // batch
constexpr int Dd  = 128;   // latent dim
constexpr int Tt  = 2048;  // timesteps
constexpr int NQn = 8;     // num quantizers
constexpr int CSc = 1024;  // codebook size

constexpr int WAVES = 4;           // waves per block (split codebook scan)
constexpr int CPW   = CSc / WAVES; // codes per wave = 256
constexpr int CHUNK = 8;           // codes staged per LDS buffer fill
constexpr int NCHUNK = CPW / CHUNK;            // 32
constexpr int CHUNK_FLOATS = CHUNK * Dd;       // 1024 floats = 4 KB

// async global->LDS, 16 B per lane per instruction (dest = base + lane*16)
__device__ inline void gload_lds16(const float* g, float* l) {
    __builtin_amdgcn_global_load_lds(
        (const __attribute__((address_space(1))) void*)g,
        (__attribute__((address_space(3))) void*)l,
        16, 0, 0);
}

// ---------------------------------------------------------------------------
// Kernel 0: precompute ||c||^2 for all NQ*CS codes into d_ws
// ---------------------------------------------------------------------------
__global__ __launch_bounds__(64) void cnorm_kernel(const float* __restrict__ cb,
                                                   float* __restrict__ cnorm) {
    int c = blockIdx.x * 64 + threadIdx.x;   // 0 .. NQ*CS-1
    const float4* p = reinterpret_cast<const float4*>(cb + (size_t)c * Dd);
    float s0 = 0.f, s1 = 0.f, s2 = 0.f, s3 = 0.f;
#pragma unroll
    for (int k = 0; k < Dd / 4; ++k) {
        float4 v = p[k];
        s0 = fmaf(v.x, v.x, s0);
        s1 = fmaf(v.y, v.y, s1);
        s2 = fmaf(v.z, v.z, s2);
        s3 = fmaf(v.w, v.w, s3);
    }
    cnorm[c] = (s0 + s1) + (s2 + s3);
}

// ---------------------------------------------------------------------------
// Kernel 1: main RVQ. Lane = one (b,t) vector, r[128] in VGPRs.
// Codebook quarter streamed through per-wave double-buffered LDS
// (global_load_lds width-16), consumed as broadcast ds_read_b128.
// ---------------------------------------------------------------------------
__global__ __launch_bounds__(256, 2) void rvq_kernel(const float* __restrict__ x,
                                                     const float* __restrict__ cb,
                                                     const float* __restrict__ cnorm,
                                                     float* __restrict__ out,
                                                     float* __restrict__ loss_part) {
    const int tid  = threadIdx.x;
    const int lane = tid & 63;
    // wave id made uniform so LDS bases / scan addresses are wave-uniform
    const int wave = __builtin_amdgcn_readfirstlane(tid >> 6);

    const int v = blockIdx.x * 64 + lane;  // global vector id in [0, B*T)
    const int b = v >> 11;                 // v / T   (T = 2048)
    const int t = v & (Tt - 1);            // v % T

    const float* xp = x + (size_t)b * Dd * Tt + t;

    // residual in registers (static indexing only)
    float r[Dd];
#pragma unroll
    for (int d = 0; d < Dd; ++d) r[d] = xp[(size_t)d * Tt];

    // per-wave double-buffered codebook staging (wave-private: no barriers)
    __shared__ float lbuf[WAVES][2][CHUNK_FLOATS];
    __shared__ float s_best[WAVES][64];
    __shared__ int   s_idx[WAVES][64];

    float loss_acc = 0.f;

    for (int q = 0; q < NQn; ++q) {
        // ||r||^2 (tree accumulation)
        float rn0 = 0.f, rn1 = 0.f, rn2 = 0.f, rn3 = 0.f;
#pragma unroll
        for (int d = 0; d < Dd; d += 4) {
            rn0 = fmaf(r[d + 0], r[d + 0], rn0);
            rn1 = fmaf(r[d + 1], r[d + 1], rn1);
            rn2 = fmaf(r[d + 2], r[d + 2], rn2);
            rn3 = fmaf(r[d + 3], r[d + 3], rn3);
        }
        const float rn = (rn0 + rn1) + (rn2 + rn3);

        const float* cbase = cb + ((size_t)q * CSc + (size_t)wave * CPW) * Dd;

        // this wave's 256 ||c||^2 values in 4 VGPRs (readlane broadcast later)
        float cnv[4];
#pragma unroll
        for (int g = 0; g < 4; ++g)
            cnv[g] = cnorm[q * CSc + wave * CPW + g * 64 + lane];

        float best = 3.4e38f;
        int   bidx = 0;

        // prologue: stage chunk 0 into buffer 0
        {
            const float* gsrc = cbase;
            float* lb = &lbuf[wave][0][0];
#pragma unroll
            for (int j = 0; j < 4; ++j)
                gload_lds16(gsrc + j * 256 + lane * 4, lb + j * 256);
        }

        for (int ch = 0; ch < NCHUNK; ++ch) {
            const int buf = ch & 1;
            // wait for current chunk's staging to land in LDS
            asm volatile("s_waitcnt vmcnt(0)" ::: "memory");
            // issue next chunk into the other buffer (latency hidden by compute)
            if (ch + 1 < NCHUNK) {
                const float* gsrc = cbase + (size_t)(ch + 1) * CHUNK_FLOATS;
                float* lb = &lbuf[wave][buf ^ 1][0];
#pragma unroll
                for (int j = 0; j < 4; ++j)
                    gload_lds16(gsrc + j * 256 + lane * 4, lb + j * 256);
            }

            const float* lc0 = &lbuf[wave][buf][0];
#pragma unroll 2
            for (int cc = 0; cc < CHUNK; ++cc) {
                const int c = ch * CHUNK + cc;
                const float4* cp = reinterpret_cast<const float4*>(lc0 + cc * Dd);
                float a0, a1, a2, a3, a4, a5, a6, a7;
                {
                    float4 u = cp[0], w = cp[1];
                    a0 = u.x * r[0]; a1 = u.y * r[1];
                    a2 = u.z * r[2]; a3 = u.w * r[3];
                    a4 = w.x * r[4]; a5 = w.y * r[5];
                    a6 = w.z * r[6]; a7 = w.w * r[7];
                }
#pragma unroll
                for (int d = 8; d < Dd; d += 8) {
                    float4 u = cp[d / 4], w = cp[d / 4 + 1];
                    a0 = fmaf(u.x, r[d + 0], a0);
                    a1 = fmaf(u.y, r[d + 1], a1);
                    a2 = fmaf(u.z, r[d + 2], a2);
                    a3 = fmaf(u.w, r[d + 3], a3);
                    a4 = fmaf(w.x, r[d + 4], a4);
                    a5 = fmaf(w.y, r[d + 5], a5);
                    a6 = fmaf(w.z, r[d + 6], a6);
                    a7 = fmaf(w.w, r[d + 7], a7);
                }
                float dot = ((a0 + a1) + (a2 + a3)) + ((a4 + a5) + (a6 + a7));
                float cn = __int_as_float(
                    __builtin_amdgcn_readlane(__float_as_int(cnv[c >> 6]),
                                              c & 63));
                // reference formula: d = ||r||^2 - 2 r.c + ||c||^2
                float dist = fmaf(-2.f, dot, rn + cn);
                // strict < : first (lowest) index wins ties, ascending scan
                if (dist < best) { best = dist; bidx = c; }
            }
        }

        s_best[wave][lane] = best;
        s_idx[wave][lane]  = wave * CPW + bidx;
        __syncthreads();

        // combine across the 4 waves, ascending wave order (= ascending code idx)
        float gbest = s_best[0][lane];
        int   gidx  = s_idx[0][lane];
#pragma unroll
        for (int w = 1; w < WAVES; ++w) {
            float bw = s_best[w][lane];
            int   iw = s_idx[w][lane];
            if (bw < gbest) { gbest = bw; gidx = iw; }
        }
        __syncthreads();  // protect LDS reuse next stage

        // update residual with selected code; accumulate loss = ||r_new||^2
        // (gidx is per-lane divergent -> per-lane vector gather)
        const float4* cw4 =
            reinterpret_cast<const float4*>(cb + ((size_t)q * CSc + gidx) * Dd);
        float l0 = 0.f, l1 = 0.f, l2 = 0.f, l3 = 0.f;
#pragma unroll
        for (int k = 0; k < Dd / 4; ++k) {
            float4 cv = cw4[k];
            float w0 = r[4 * k + 0] - cv.x;
            float w1 = r[4 * k + 1] - cv.y;
            float w2 = r[4 * k + 2] - cv.z;
            float w3 = r[4 * k + 3] - cv.w;
            r[4 * k + 0] = w0;
            r[4 * k + 1] = w1;
            r[4 * k + 2] = w2;
            r[4 * k + 3] = w3;
            l0 = fmaf(w0, w0, l0);
            l1 = fmaf(w1, w1, l1);
            l2 = fmaf(w2, w2, l2);
            l3 = fmaf(w3, w3, l3);
        }
        loss_acc += (l0 + l1) + (l2 + l3);
    }

    // Epilogue: q_sum = x0 - r_final (wave 0 writes; all waves hold identical r)
    if (wave == 0) {
        float* op = out + (size_t)b * Dd * Tt + t;
#pragma unroll
        for (int d = 0; d < Dd; ++d)
            op[(size_t)d * Tt] = xp[(size_t)d * Tt] - r[d];

        // reduce loss across the 64 lanes of wave 0 (deterministic)
        float ls = loss_acc;
#pragma unroll
        for (int off = 32; off > 0; off >>= 1) ls += __shfl_down(ls, off, 64);
        if (lane == 0) loss_part[blockIdx.x] = ls;
    }
}

// ---------------------------------------------------------------------------
// Kernel 2: deterministic loss reduction: 32 block-partials per batch element
// ---------------------------------------------------------------------------
__global__ __launch_bounds__(64) void loss_kernel(const float* __restrict__ part,
                                                  float* __restrict__ out_loss) {
    int b = threadIdx.x;
    if (b < Bb) {
        float s = 0.f;
        const int ppb = Tt / 64;  // 32 partials per batch element
        for (int k = 0; k < ppb; ++k) s += part[b * ppb + k];
        out_loss[b] = s * (1.0f / ((float)Dd * (float)Tt));
    }
}

// ---------------------------------------------------------------------------
extern "C" void kernel_launch(void* const* d_in, const int* in_sizes, int n_in,
                              void* d_out, int out_size, void* d_ws, size_t ws_size,
                              hipStream_t stream) {
    const float* x  = (const float*)d_in[0];   // [B, D, T]
    const float* cb = (const float*)d_in[1];   // [NQ, CS, D]
    float* out = (float*)d_out;                // [B*D*T] q_sum ++ [B] loss_sum

    // workspace layout: cnorm[NQ*CS] then loss partials[B*T/64]
    float* cnorm = (float*)d_ws;
    float* part  = cnorm + NQn * CSc;

    cnorm_kernel<<<(NQn * CSc) / 64, 64, 0, stream>>>(cb, cnorm);

    const int nblocks = (Bb * Tt) / 64;  // 512
    rvq_kernel<<<nblocks, WAVES * 64, 0, stream>>>(x, cb, cnorm, out, part);

    loss_kernel<<<1, 64, 0, stream>>>(part, out + (size_t)Bb * Dd * Tt);
}

// Round 5
// 1390.677 us; speedup vs baseline: 3.6997x; 1.3251x over previous
//
#include <hip/hip_runtime.h>

// Problem constants
constexpr int Bb  = 16;
constexpr int Dd  = 128;
constexpr int Tt  = 2048;
constexpr int NQn = 8;
constexpr int CSc = 1024;

constexpr int TB   = 64;    // t per block
constexpr int ROWP = 136;   // padded split-row length in ushorts (272 B)

typedef __attribute__((ext_vector_type(8))) short  short8;
typedef __attribute__((ext_vector_type(4))) short  short4v;
typedef __attribute__((ext_vector_type(4))) float  f32x4;

// ---- bf16 helpers (RNE) ----
__device__ inline ushort f2bf(float f) {
    union { float f; unsigned u; } v; v.f = f;
    unsigned r = v.u + 0x7FFFu + ((v.u >> 16) & 1u);
    return (ushort)(r >> 16);
}
__device__ inline float bf2f(ushort h) {
    union { unsigned u; float f; } v; v.u = ((unsigned)h) << 16;
    return v.f;
}
__device__ inline void bsplit(float xv, ushort& h, ushort& m, ushort& l) {
    h = f2bf(xv);            float hf = bf2f(h);
    float r1 = xv - hf;      m = f2bf(r1);
    float mf = bf2f(m);      l = f2bf(r1 - mf);
}

// ---------------------------------------------------------------------------
// Kernel 0: split codebook fp32 -> 3x bf16 planes + exact fp32 ||c||^2
// ---------------------------------------------------------------------------
__global__ __launch_bounds__(64) void split_kernel(const float* __restrict__ cb,
                                                   ushort* __restrict__ cbH,
                                                   ushort* __restrict__ cbM,
                                                   ushort* __restrict__ cbL,
                                                   float* __restrict__ cn) {
    int c = blockIdx.x * 64 + threadIdx.x;          // 0..NQ*CS-1
    const float* p = cb + (size_t)c * Dd;
    float s0 = 0.f, s1 = 0.f, s2 = 0.f, s3 = 0.f;
#pragma unroll
    for (int d = 0; d < Dd; d += 4) {
        float4 v = *(const float4*)(p + d);
        s0 = fmaf(v.x, v.x, s0);
        s1 = fmaf(v.y, v.y, s1);
        s2 = fmaf(v.z, v.z, s2);
        s3 = fmaf(v.w, v.w, s3);
        short4v h4, m4, l4;
        ushort hh, mm, ll;
        bsplit(v.x, hh, mm, ll); h4[0] = (short)hh; m4[0] = (short)mm; l4[0] = (short)ll;
        bsplit(v.y, hh, mm, ll); h4[1] = (short)hh; m4[1] = (short)mm; l4[1] = (short)ll;
        bsplit(v.z, hh, mm, ll); h4[2] = (short)hh; m4[2] = (short)mm; l4[2] = (short)ll;
        bsplit(v.w, hh, mm, ll); h4[3] = (short)hh; m4[3] = (short)mm; l4[3] = (short)ll;
        *(short4v*)&cbH[(size_t)c * Dd + d] = h4;
        *(short4v*)&cbM[(size_t)c * Dd + d] = m4;
        *(short4v*)&cbL[(size_t)c * Dd + d] = l4;
    }
    cn[c] = (s0 + s1) + (s2 + s3);
}

// ---------------------------------------------------------------------------
// Kernel 1: MFMA RVQ. 512 threads (8 waves), 64 t per block.
// Wave w: t-tile nq = w>>1 (16 t), code-half ch = w&1 (512 codes).
// dot[c,t] via 6-pass 3-way-bf16-split MFMA (16x16x32). Residual kept as
// 3 bf16 planes in LDS; updated in fp32 with the ORIGINAL fp32 codebook.
// ---------------------------------------------------------------------------
__global__ __launch_bounds__(512, 2) void rvq_mfma(const float* __restrict__ x,
                                                   const float* __restrict__ cb,
                                                   const ushort* __restrict__ cbH,
                                                   const ushort* __restrict__ cbM,
                                                   const ushort* __restrict__ cbL,
                                                   const float* __restrict__ cn_g,
                                                   float* __restrict__ out,
                                                   float* __restrict__ part) {
    __shared__ ushort sH[TB][ROWP];
    __shared__ ushort sM[TB][ROWP];
    __shared__ ushort sL[TB][ROWP];
    __shared__ float  cn_lds[CSc];
    __shared__ float  s_rnp[TB][8];
    __shared__ float  s_best[8][16];
    __shared__ int    s_idx[8][16];
    __shared__ int    s_gidx[TB];
    __shared__ float  s_red[8];

    const int tid  = threadIdx.x;
    const int lane = tid & 63;
    const int w    = __builtin_amdgcn_readfirstlane(tid >> 6);
    const int lrow = lane & 15;        // frag row/col index
    const int lk8  = lane >> 4;        // frag k-group (0..3)
    const int nq   = w >> 1;           // t-tile (16 t)
    const int ch   = w & 1;            // code half
    const int c0base = ch * 512;
    const int trow = nq * 16 + lrow;   // this lane's t (local)

    const int t0  = blockIdx.x * TB;
    const int b   = t0 >> 11;
    const int tb0 = t0 & (Tt - 1);
    const size_t xbase = (size_t)b * Dd * Tt;

    // ---------------- init: x -> split planes ----------------
    {
        const int tq = tid & 15, dblk = tid >> 4;   // 4 t x 4 d per thread
        float rr[4][4];                              // [jd][tl]
#pragma unroll
        for (int jd = 0; jd < 4; ++jd) {
            float4 v = *(const float4*)(x + xbase + (size_t)(dblk * 4 + jd) * Tt + tb0 + tq * 4);
            rr[jd][0] = v.x; rr[jd][1] = v.y; rr[jd][2] = v.z; rr[jd][3] = v.w;
        }
#pragma unroll
        for (int tl = 0; tl < 4; ++tl) {
            short4v h4, m4, l4;
#pragma unroll
            for (int jd = 0; jd < 4; ++jd) {
                ushort hh, mm, ll;
                bsplit(rr[jd][tl], hh, mm, ll);
                h4[jd] = (short)hh; m4[jd] = (short)mm; l4[jd] = (short)ll;
            }
            *(short4v*)&sH[tq * 4 + tl][dblk * 4] = h4;
            *(short4v*)&sM[tq * 4 + tl][dblk * 4] = m4;
            *(short4v*)&sL[tq * 4 + tl][dblk * 4] = l4;
        }
    }
    __syncthreads();
    // ---------------- init rn ----------------
    {
        const int t = tid >> 3, sub = tid & 7;      // 16 dims per thread
        float l0 = 0.f, l1 = 0.f, l2 = 0.f, l3 = 0.f;
#pragma unroll
        for (int jj = 0; jj < 2; ++jj) {
            short8 h8 = *(const short8*)&sH[t][sub * 16 + jj * 8];
            short8 m8 = *(const short8*)&sM[t][sub * 16 + jj * 8];
            short8 l8 = *(const short8*)&sL[t][sub * 16 + jj * 8];
#pragma unroll
            for (int e = 0; e < 8; e += 4) {
                float v0 = (bf2f((ushort)h8[e + 0]) + bf2f((ushort)m8[e + 0])) + bf2f((ushort)l8[e + 0]);
                float v1 = (bf2f((ushort)h8[e + 1]) + bf2f((ushort)m8[e + 1])) + bf2f((ushort)l8[e + 1]);
                float v2 = (bf2f((ushort)h8[e + 2]) + bf2f((ushort)m8[e + 2])) + bf2f((ushort)l8[e + 2]);
                float v3 = (bf2f((ushort)h8[e + 3]) + bf2f((ushort)m8[e + 3])) + bf2f((ushort)l8[e + 3]);
                l0 = fmaf(v0, v0, l0); l1 = fmaf(v1, v1, l1);
                l2 = fmaf(v2, v2, l2); l3 = fmaf(v3, v3, l3);
            }
        }
        s_rnp[t][sub] = (l0 + l1) + (l2 + l3);
    }
    __syncthreads();

    float loss_acc = 0.f;

#define LOADA(Abuf, c0v)                                                            \
    {                                                                               \
        const size_t abase = ((size_t)q * CSc + (c0v) + lrow) * Dd + lk8 * 8;       \
        _Pragma("unroll") for (int kk = 0; kk < 4; ++kk) {                          \
            Abuf[0][kk] = *(const short8*)(cbH + abase + kk * 32);                  \
            Abuf[1][kk] = *(const short8*)(cbM + abase + kk * 32);                  \
            Abuf[2][kk] = *(const short8*)(cbL + abase + kk * 32);                  \
        }                                                                           \
    }

#define COMPUTE(Abuf, c0v)                                                          \
    {                                                                               \
        f32x4 accA = {0.f, 0.f, 0.f, 0.f};                                          \
        f32x4 accB = {0.f, 0.f, 0.f, 0.f};                                          \
        _Pragma("unroll") for (int kk = 0; kk < 4; ++kk) {                          \
            accA = __builtin_amdgcn_mfma_f32_16x16x32_bf16(Abuf[0][kk], Bf[0][kk], accA, 0, 0, 0); \
            accB = __builtin_amdgcn_mfma_f32_16x16x32_bf16(Abuf[1][kk], Bf[1][kk], accB, 0, 0, 0); \
        }                                                                           \
        _Pragma("unroll") for (int kk = 0; kk < 4; ++kk) {                          \
            accA = __builtin_amdgcn_mfma_f32_16x16x32_bf16(Abuf[0][kk], Bf[1][kk], accA, 0, 0, 0); \
            accB = __builtin_amdgcn_mfma_f32_16x16x32_bf16(Abuf[0][kk], Bf[2][kk], accB, 0, 0, 0); \
        }                                                                           \
        _Pragma("unroll") for (int kk = 0; kk < 4; ++kk) {                          \
            accA = __builtin_amdgcn_mfma_f32_16x16x32_bf16(Abuf[1][kk], Bf[0][kk], accA, 0, 0, 0); \
            accB = __builtin_amdgcn_mfma_f32_16x16x32_bf16(Abuf[2][kk], Bf[0][kk], accB, 0, 0, 0); \
        }                                                                           \
        f32x4 accT = accA + accB;                                                   \
        f32x4 cn4 = *(const f32x4*)&cn_lds[(c0v) + (lk8 << 2)];                     \
        _Pragma("unroll") for (int rr2 = 0; rr2 < 4; ++rr2) {                       \
            float dd = fmaf(-2.f, accT[rr2], rn + cn4[rr2]);                        \
            int cid = (c0v) + (lk8 << 2) + rr2;                                     \
            if (dd < best) { best = dd; bidx = cid; }                               \
        }                                                                           \
    }

    for (int q = 0; q < NQn; ++q) {
        // stage cn into LDS
        *(float2*)&cn_lds[tid * 2] = *(const float2*)(cn_g + (size_t)q * CSc + tid * 2);
        __syncthreads();

        // B-fragments (residual splits) for this wave's 16 t, once per stage
        short8 Bf[3][4];
#pragma unroll
        for (int kk = 0; kk < 4; ++kk) {
            Bf[0][kk] = *(const short8*)&sH[trow][kk * 32 + lk8 * 8];
            Bf[1][kk] = *(const short8*)&sM[trow][kk * 32 + lk8 * 8];
            Bf[2][kk] = *(const short8*)&sL[trow][kk * 32 + lk8 * 8];
        }
        float rn;
        {
            f32x4 p0 = *(const f32x4*)&s_rnp[trow][0];
            f32x4 p1 = *(const f32x4*)&s_rnp[trow][4];
            rn = ((p0[0] + p0[1]) + (p0[2] + p0[3])) + ((p1[0] + p1[1]) + (p1[2] + p1[3]));
        }

        float best = 3.4e38f;
        int   bidx = 0;

        short8 A0[3][4], A1[3][4];
        LOADA(A0, c0base);
        for (int ct = 0; ct < 32; ct += 2) {
            const int c0 = c0base + ct * 16;
            LOADA(A1, c0 + 16);
            COMPUTE(A0, c0);
            if (ct + 2 < 32) LOADA(A0, c0 + 32);
            COMPUTE(A1, c0 + 16);
        }

        // reduce argmin across the 4 lane-groups (t fixed = trow)
#pragma unroll
        for (int mlg = 16; mlg <= 32; mlg <<= 1) {
            float ob = __shfl_xor(best, mlg, 64);
            int   oi = __shfl_xor(bidx, mlg, 64);
            if (ob < best || (ob == best && oi < bidx)) { best = ob; bidx = oi; }
        }
        if (lk8 == 0) { s_best[w][lrow] = best; s_idx[w][lrow] = bidx; }
        __syncthreads();

        // combine code halves (ascending idx tie-break = first-index-wins)
        if (tid < TB) {
            int t = tid, tq2 = t >> 4, sl = t & 15;
            float b0 = s_best[tq2 * 2][sl], b1 = s_best[tq2 * 2 + 1][sl];
            int   i0 = s_idx[tq2 * 2][sl], i1 = s_idx[tq2 * 2 + 1][sl];
            s_gidx[t] = (b1 < b0) ? i1 : i0;   // i1 > i0 always, so tie keeps i0
        }
        __syncthreads();

        // residual update (fp32, original codebook) + re-split + rn + loss
        {
            const int t = tid >> 3, sub = tid & 7;
            const int g = s_gidx[t];
            const float* cp = cb + ((size_t)q * CSc + g) * Dd + sub * 16;
            float rv[16];
#pragma unroll
            for (int jj = 0; jj < 2; ++jj) {
                short8 h8 = *(const short8*)&sH[t][sub * 16 + jj * 8];
                short8 m8 = *(const short8*)&sM[t][sub * 16 + jj * 8];
                short8 l8 = *(const short8*)&sL[t][sub * 16 + jj * 8];
#pragma unroll
                for (int e = 0; e < 8; ++e)
                    rv[jj * 8 + e] = (bf2f((ushort)h8[e]) + bf2f((ushort)m8[e])) + bf2f((ushort)l8[e]);
            }
            float l0 = 0.f, l1 = 0.f, l2 = 0.f, l3 = 0.f;
#pragma unroll
            for (int k2 = 0; k2 < 4; ++k2) {
                float4 cv = *(const float4*)(cp + k2 * 4);
                float w0 = rv[k2 * 4 + 0] - cv.x;
                float w1 = rv[k2 * 4 + 1] - cv.y;
                float w2 = rv[k2 * 4 + 2] - cv.z;
                float w3 = rv[k2 * 4 + 3] - cv.w;
                rv[k2 * 4 + 0] = w0; rv[k2 * 4 + 1] = w1;
                rv[k2 * 4 + 2] = w2; rv[k2 * 4 + 3] = w3;
                l0 = fmaf(w0, w0, l0); l1 = fmaf(w1, w1, l1);
                l2 = fmaf(w2, w2, l2); l3 = fmaf(w3, w3, l3);
            }
            float rnp = (l0 + l1) + (l2 + l3);
            loss_acc += rnp;
            s_rnp[t][sub] = rnp;
#pragma unroll
            for (int jj = 0; jj < 2; ++jj) {
                short8 h8, m8, l8;
#pragma unroll
                for (int e = 0; e < 8; ++e) {
                    ushort hh, mm, ll;
                    bsplit(rv[jj * 8 + e], hh, mm, ll);
                    h8[e] = (short)hh; m8[e] = (short)mm; l8[e] = (short)ll;
                }
                *(short8*)&sH[t][sub * 16 + jj * 8] = h8;
                *(short8*)&sM[t][sub * 16 + jj * 8] = m8;
                *(short8*)&sL[t][sub * 16 + jj * 8] = l8;
            }
        }
        __syncthreads();
    }

    // ---------------- epilogue: q_sum = x - r_final ----------------
    {
        const int tq = tid & 15, dblk = tid >> 4;
        float rr[4][4];  // [tl][jd]
#pragma unroll
        for (int tl = 0; tl < 4; ++tl) {
            short4v h4 = *(const short4v*)&sH[tq * 4 + tl][dblk * 4];
            short4v m4 = *(const short4v*)&sM[tq * 4 + tl][dblk * 4];
            short4v l4 = *(const short4v*)&sL[tq * 4 + tl][dblk * 4];
#pragma unroll
            for (int jd = 0; jd < 4; ++jd)
                rr[tl][jd] = (bf2f((ushort)h4[jd]) + bf2f((ushort)m4[jd])) + bf2f((ushort)l4[jd]);
        }
#pragma unroll
        for (int jd = 0; jd < 4; ++jd) {
            size_t off = xbase + (size_t)(dblk * 4 + jd) * Tt + tb0 + tq * 4;
            float4 xv = *(const float4*)(x + off);
            float4 ov;
            ov.x = xv.x - rr[0][jd];
            ov.y = xv.y - rr[1][jd];
            ov.z = xv.z - rr[2][jd];
            ov.w = xv.w - rr[3][jd];
            *(float4*)(out + off) = ov;
        }
    }

    // ---------------- loss partial ----------------
    {
        float ls = loss_acc;
#pragma unroll
        for (int off = 32; off > 0; off >>= 1) ls += __shfl_down(ls, off, 64);
        if (lane == 0) s_red[w] = ls;
    }
    __syncthreads();
    if (tid == 0) {
        part[blockIdx.x] = ((s_red[0] + s_red[1]) + (s_red[2] + s_red[3])) +
                           ((s_red[4] + s_red[5]) + (s_red[6] + s_red[7]));
    }
#undef LOADA
#undef COMPUTE
}

// ---------------------------------------------------------------------------
// Kernel 2: deterministic loss reduction (32 block-partials per batch element)
// ---------------------------------------------------------------------------
__global__ __launch_bounds__(64) void loss_kernel(const float* __restrict__ part,
                                                  float* __restrict__ out_loss) {
    int b = threadIdx.x;
    if (b < Bb) {
        float s = 0.f;
        const int ppb = Tt / TB;  // 32
        for (int k = 0; k < ppb; ++k) s += part[b * ppb + k];
        out_loss[b] = s * (1.0f / ((float)Dd * (float)Tt));
    }
}

// ---------------------------------------------------------------------------
extern "C" void kernel_launch(void* const* d_in, const int* in_sizes, int n_in,
                              void* d_out, int out_size, void* d_ws, size_t ws_size,
                              hipStream_t stream) {
    const float* x  = (const float*)d_in[0];   // [B, D, T]
    const float* cb = (const float*)d_in[1];   // [NQ, CS, D]
    float* out = (float*)d_out;                // [B*D*T] q_sum ++ [B] loss_sum

    // workspace: cn[8192] f32 | part[512] f32 | cbH | cbM | cbL (bf16 planes)
    float*  cn   = (float*)d_ws;
    float*  part = cn + NQn * CSc;
    ushort* cbH  = (ushort*)(part + 512);
    ushort* cbM  = cbH + (size_t)NQn * CSc * Dd;
    ushort* cbL  = cbM + (size_t)NQn * CSc * Dd;

    split_kernel<<<(NQn * CSc) / 64, 64, 0, stream>>>(cb, cbH, cbM, cbL, cn);

    const int nblocks = (Bb * Tt) / TB;  // 512
    rvq_mfma<<<nblocks, 512, 0, stream>>>(x, cb, cbH, cbM, cbL, cn, out, part);

    loss_kernel<<<1, 64, 0, stream>>>(part, out + (size_t)Bb * Dd * Tt);
}

// Round 6
// 589.160 us; speedup vs baseline: 8.7329x; 2.3604x over previous
//
#include <hip/hip_runtime.h>

// Problem constants
constexpr int Bb  = 16;
constexpr int Dd  = 128;
constexpr int Tt  = 2048;
constexpr int NQn = 8;
constexpr int CSc = 1024;

constexpr int TB  = 64;     // t per block
constexpr int NCH = 32;     // 16-code chunks per half per stage
constexpr int CHU = 6144;   // ushorts per staged chunk (16 codes x 128 d x 3 planes = 12 KB)

typedef __attribute__((ext_vector_type(8))) short  short8;
typedef __attribute__((ext_vector_type(4))) float  f32x4;

// ---- bf16 helpers (RNE) ----
__device__ inline ushort f2bf(float f) {
    union { float f; unsigned u; } v; v.f = f;
    unsigned r = v.u + 0x7FFFu + ((v.u >> 16) & 1u);
    return (ushort)(r >> 16);
}
__device__ inline float bf2f(ushort h) {
    union { unsigned u; float f; } v; v.u = ((unsigned)h) << 16;
    return v.f;
}
__device__ inline void bsplit(float xv, ushort& h, ushort& m, ushort& l) {
    h = f2bf(xv);            float hf = bf2f(h);
    float r1 = xv - hf;      m = f2bf(r1);
    float mf = bf2f(m);      l = f2bf(r1 - mf);
}

// async global->LDS, 16 B/lane (LDS dest = wave-uniform base + lane*16)
__device__ inline void gload_lds16(const ushort* g, ushort* l) {
    __builtin_amdgcn_global_load_lds(
        (const __attribute__((address_space(1))) void*)g,
        (__attribute__((address_space(3))) void*)l, 16, 0, 0);
}

// ---------------------------------------------------------------------------
// Kernel 0: split codebook fp32 -> 3x bf16 planes, FRAGMENT-ORDERED per
// 16-code chunk: chunk gc stores, for (p,kk,lane), the short8 a reading lane
// wants: code = chunk*16 + (lane&15), dims kk*32 + (lane>>4)*8 + j.
// Also exact fp32 ||c||^2.
// ---------------------------------------------------------------------------
__global__ __launch_bounds__(64) void split_kernel(const float* __restrict__ cb,
                                                   ushort* __restrict__ cbS,
                                                   float* __restrict__ cn) {
    const int c      = blockIdx.x * 64 + threadIdx.x;  // global code id (q*1024+cloc)
    const int chunkg = c >> 4;                          // global chunk id
    const int lrow   = c & 15;
    const float* p   = cb + (size_t)c * Dd;
    const size_t cbase = (size_t)chunkg * CHU;

    float s0 = 0.f, s1 = 0.f, s2 = 0.f, s3 = 0.f;
#pragma unroll
    for (int kk = 0; kk < 4; ++kk) {
#pragma unroll
        for (int hi = 0; hi < 4; ++hi) {
            const int lanew = hi * 16 + lrow;
            short8 h8, m8, l8;
#pragma unroll
            for (int jj = 0; jj < 8; jj += 4) {
                float4 v = *(const float4*)(p + kk * 32 + hi * 8 + jj);
                s0 = fmaf(v.x, v.x, s0);
                s1 = fmaf(v.y, v.y, s1);
                s2 = fmaf(v.z, v.z, s2);
                s3 = fmaf(v.w, v.w, s3);
                ushort hh, mm, ll;
                bsplit(v.x, hh, mm, ll); h8[jj + 0] = (short)hh; m8[jj + 0] = (short)mm; l8[jj + 0] = (short)ll;
                bsplit(v.y, hh, mm, ll); h8[jj + 1] = (short)hh; m8[jj + 1] = (short)mm; l8[jj + 1] = (short)ll;
                bsplit(v.z, hh, mm, ll); h8[jj + 2] = (short)hh; m8[jj + 2] = (short)mm; l8[jj + 2] = (short)ll;
                bsplit(v.w, hh, mm, ll); h8[jj + 3] = (short)hh; m8[jj + 3] = (short)mm; l8[jj + 3] = (short)ll;
            }
            *(short8*)&cbS[cbase + (size_t)((0 * 4 + kk) * 64 + lanew) * 8] = h8;
            *(short8*)&cbS[cbase + (size_t)((1 * 4 + kk) * 64 + lanew) * 8] = m8;
            *(short8*)&cbS[cbase + (size_t)((2 * 4 + kk) * 64 + lanew) * 8] = l8;
        }
    }
    cn[c] = (s0 + s1) + (s2 + s3);
}

// ---------------------------------------------------------------------------
// Kernel 1: MFMA RVQ. 512 threads = 8 waves = 4 t-tiles(16t) x 2 code-halves.
// Residual fp32 + bf16-split B-fragments live in REGISTERS (lane owns 32 dims
// of one t). Codebook chunks staged global->LDS (shared by the half's 4
// waves), double-buffered, consumed as conflict-free lane-linear ds_read_b128.
// ---------------------------------------------------------------------------
__global__ __launch_bounds__(512) void rvq_mfma(const float* __restrict__ x,
                                                const float* __restrict__ cb,
                                                const ushort* __restrict__ cbS,
                                                const float* __restrict__ cn_g,
                                                float* __restrict__ out,
                                                float* __restrict__ part) {
    __shared__ __align__(16) ushort sA[2][2][CHU];   // [half][dbuf][chunk] = 48 KB
    __shared__ __align__(16) float  cn_lds[CSc];
    __shared__ float s_best[8][16];
    __shared__ int   s_idx[8][16];
    __shared__ int   s_gidx[TB];
    __shared__ float s_red[4];

    const int tid  = threadIdx.x;
    const int lane = tid & 63;
    const int w    = __builtin_amdgcn_readfirstlane(tid >> 6);
    const int tt   = w >> 1;          // t-tile 0..3
    const int h    = w & 1;           // code half
    const int lrow = lane & 15;       // t within tile / code row within A-tile
    const int hi   = lane >> 4;       // k-group 0..3

    const int t0  = blockIdx.x * TB;
    const int b   = t0 >> 11;
    const int tb0 = t0 & (Tt - 1);
    const int tg  = tb0 + tt * 16 + lrow;      // t within batch row
    const size_t xbase = (size_t)b * Dd * Tt;

    // lane's fp32 residual: dims d = kk*32 + hi*8 + j for t = tg
    float r[4][8];
#pragma unroll
    for (int kk = 0; kk < 4; ++kk)
#pragma unroll
        for (int j = 0; j < 8; ++j)
            r[kk][j] = x[xbase + (size_t)(kk * 32 + hi * 8 + j) * Tt + tg];

    float loss_acc = 0.f;

#pragma unroll 1
    for (int q = 0; q < NQn; ++q) {
        // ---- B-fragments (split of r) + ||r||^2 ----
        short8 Bf[3][4];
        float p0 = 0.f, p1 = 0.f, p2 = 0.f, p3 = 0.f;
#pragma unroll
        for (int kk = 0; kk < 4; ++kk) {
            short8 h8, m8, l8;
#pragma unroll
            for (int j = 0; j < 8; ++j) {
                float v = r[kk][j];
                ushort hh, mm, ll;
                bsplit(v, hh, mm, ll);
                h8[j] = (short)hh; m8[j] = (short)mm; l8[j] = (short)ll;
                if ((j & 3) == 0)      p0 = fmaf(v, v, p0);
                else if ((j & 3) == 1) p1 = fmaf(v, v, p1);
                else if ((j & 3) == 2) p2 = fmaf(v, v, p2);
                else                   p3 = fmaf(v, v, p3);
            }
            Bf[0][kk] = h8; Bf[1][kk] = m8; Bf[2][kk] = l8;
        }
        float rnp = (p0 + p1) + (p2 + p3);
        rnp += __shfl_xor(rnp, 16, 64);     // sum over the 4 lanes of this t
        rnp += __shfl_xor(rnp, 32, 64);     // (commutative adds -> identical bits)
        const float rn = rnp;

        // ---- stage cn for this quantizer ----
        *(float2*)&cn_lds[tid * 2] = *(const float2*)&cn_g[(size_t)q * CSc + tid * 2];

        // ---- prologue: stage chunk 0 -> buf 0 (each wave stages its 3 KB) ----
        {
            const int gc = q * 64 + h * 32;
            const ushort* g = cbS + (size_t)gc * CHU + (tt * 3) * 512 + lane * 8;
            ushort* dl = &sA[h][0][(tt * 3) * 512];
#pragma unroll
            for (int i = 0; i < 3; ++i) gload_lds16(g + i * 512, dl + i * 512);
        }
        asm volatile("s_waitcnt vmcnt(0)" ::: "memory");
        __syncthreads();

        float best = 3.4e38f;
        int   bidx = 0;

#pragma unroll 1
        for (int ct = 0; ct < NCH; ++ct) {
            // issue next chunk's staging (hidden under this chunk's MFMAs)
            if (ct + 1 < NCH) {
                const int gc = q * 64 + h * 32 + ct + 1;
                const ushort* g = cbS + (size_t)gc * CHU + (tt * 3) * 512 + lane * 8;
                ushort* dl = &sA[h][(ct + 1) & 1][(tt * 3) * 512];
#pragma unroll
                for (int i = 0; i < 3; ++i) gload_lds16(g + i * 512, dl + i * 512);
            }

            // A-fragments: lane-linear ds_read_b128, conflict-free
            const ushort* ab = &sA[h][ct & 1][0];
            short8 A[3][4];
#pragma unroll
            for (int p = 0; p < 3; ++p)
#pragma unroll
                for (int kk = 0; kk < 4; ++kk)
                    A[p][kk] = *(const short8*)&ab[(size_t)((p * 4 + kk) * 64 + lane) * 8];

            // 6-pass split MFMA (HH,MM | HM,HL | MH,LH) — same as passing round 5
            f32x4 accA = {0.f, 0.f, 0.f, 0.f};
            f32x4 accB = {0.f, 0.f, 0.f, 0.f};
            __builtin_amdgcn_s_setprio(1);
#pragma unroll
            for (int kk = 0; kk < 4; ++kk) {
                accA = __builtin_amdgcn_mfma_f32_16x16x32_bf16(A[0][kk], Bf[0][kk], accA, 0, 0, 0);
                accB = __builtin_amdgcn_mfma_f32_16x16x32_bf16(A[1][kk], Bf[1][kk], accB, 0, 0, 0);
            }
#pragma unroll
            for (int kk = 0; kk < 4; ++kk) {
                accA = __builtin_amdgcn_mfma_f32_16x16x32_bf16(A[0][kk], Bf[1][kk], accA, 0, 0, 0);
                accB = __builtin_amdgcn_mfma_f32_16x16x32_bf16(A[0][kk], Bf[2][kk], accB, 0, 0, 0);
            }
#pragma unroll
            for (int kk = 0; kk < 4; ++kk) {
                accA = __builtin_amdgcn_mfma_f32_16x16x32_bf16(A[1][kk], Bf[0][kk], accA, 0, 0, 0);
                accB = __builtin_amdgcn_mfma_f32_16x16x32_bf16(A[2][kk], Bf[0][kk], accB, 0, 0, 0);
            }
            __builtin_amdgcn_s_setprio(0);

            f32x4 accT = accA + accB;
            const int c0 = h * 512 + ct * 16;
            f32x4 cn4 = *(const f32x4*)&cn_lds[c0 + hi * 4];
#pragma unroll
            for (int reg = 0; reg < 4; ++reg) {
                float dd = fmaf(-2.f, accT[reg], rn + cn4[reg]);   // ||r||^2-2rc+||c||^2
                int cid = c0 + hi * 4 + reg;                       // ascending in reg
                if (dd < best) { best = dd; bidx = cid; }          // strict <: first wins
            }

            asm volatile("s_waitcnt vmcnt(0)" ::: "memory");
            __syncthreads();
        }

        // ---- lexicographic argmin across the 4 k-groups (t fixed) ----
#pragma unroll
        for (int m = 16; m <= 32; m <<= 1) {
            float ob = __shfl_xor(best, m, 64);
            int   oi = __shfl_xor(bidx, m, 64);
            if (ob < best || (ob == best && oi < bidx)) { best = ob; bidx = oi; }
        }
        if (hi == 0) { s_best[w][lrow] = best; s_idx[w][lrow] = bidx; }
        __syncthreads();

        // combine code halves (i1 > i0 always: tie keeps lower index)
        if (tid < TB) {
            int t = tid, tq2 = t >> 4, sl = t & 15;
            float b0 = s_best[tq2 * 2][sl], b1 = s_best[tq2 * 2 + 1][sl];
            int   i0 = s_idx[tq2 * 2][sl],  i1 = s_idx[tq2 * 2 + 1][sl];
            s_gidx[t] = (b1 < b0) ? i1 : i0;
        }
        __syncthreads();

        // ---- residual update (exact fp32, original codebook) + loss ----
        {
            const int g = s_gidx[tt * 16 + lrow];
            const float* cp = cb + ((size_t)q * CSc + g) * Dd + hi * 8;
            float l0 = 0.f, l1 = 0.f, l2 = 0.f, l3 = 0.f;
#pragma unroll
            for (int kk = 0; kk < 4; ++kk) {
                float4 ca = *(const float4*)(cp + kk * 32);
                float4 cb4 = *(const float4*)(cp + kk * 32 + 4);
                float w0 = r[kk][0] - ca.x,  w1 = r[kk][1] - ca.y;
                float w2 = r[kk][2] - ca.z,  w3 = r[kk][3] - ca.w;
                float w4 = r[kk][4] - cb4.x, w5 = r[kk][5] - cb4.y;
                float w6 = r[kk][6] - cb4.z, w7 = r[kk][7] - cb4.w;
                r[kk][0] = w0; r[kk][1] = w1; r[kk][2] = w2; r[kk][3] = w3;
                r[kk][4] = w4; r[kk][5] = w5; r[kk][6] = w6; r[kk][7] = w7;
                l0 = fmaf(w0, w0, l0); l1 = fmaf(w1, w1, l1);
                l2 = fmaf(w2, w2, l2); l3 = fmaf(w3, w3, l3);
                l0 = fmaf(w4, w4, l0); l1 = fmaf(w5, w5, l1);
                l2 = fmaf(w6, w6, l2); l3 = fmaf(w7, w7, l3);
            }
            if (h == 0) loss_acc += (l0 + l1) + (l2 + l3);   // each t/dim counted once
        }
    }

    // ---- epilogue: q_sum = x0 - r_final (h==0 waves only) ----
    if (h == 0) {
#pragma unroll
        for (int kk = 0; kk < 4; ++kk)
#pragma unroll
            for (int j = 0; j < 8; ++j) {
                size_t off = xbase + (size_t)(kk * 32 + hi * 8 + j) * Tt + tg;
                out[off] = x[off] - r[kk][j];
            }
        float ls = loss_acc;
#pragma unroll
        for (int off = 32; off > 0; off >>= 1) ls += __shfl_down(ls, off, 64);
        if (lane == 0) s_red[tt] = ls;
    }
    __syncthreads();
    if (tid == 0)
        part[blockIdx.x] = (s_red[0] + s_red[1]) + (s_red[2] + s_red[3]);
}

// ---------------------------------------------------------------------------
// Kernel 2: deterministic loss reduction (32 block-partials per batch element)
// ---------------------------------------------------------------------------
__global__ __launch_bounds__(64) void loss_kernel(const float* __restrict__ part,
                                                  float* __restrict__ out_loss) {
    int b = threadIdx.x;
    if (b < Bb) {
        float s = 0.f;
        const int ppb = Tt / TB;  // 32
        for (int k = 0; k < ppb; ++k) s += part[b * ppb + k];
        out_loss[b] = s * (1.0f / ((float)Dd * (float)Tt));
    }
}

// ---------------------------------------------------------------------------
extern "C" void kernel_launch(void* const* d_in, const int* in_sizes, int n_in,
                              void* d_out, int out_size, void* d_ws, size_t ws_size,
                              hipStream_t stream) {
    const float* x  = (const float*)d_in[0];   // [B, D, T]
    const float* cb = (const float*)d_in[1];   // [NQ, CS, D]
    float* out = (float*)d_out;                // [B*D*T] q_sum ++ [B] loss_sum

    // workspace: cn[8192] f32 | part[512] f32 | cbS fragment-ordered bf16 planes (6 MB)
    float*  cn   = (float*)d_ws;
    float*  part = cn + NQn * CSc;
    ushort* cbS  = (ushort*)(part + 512);

    split_kernel<<<(NQn * CSc) / 64, 64, 0, stream>>>(cb, cbS, cn);

    const int nblocks = (Bb * Tt) / TB;  // 512
    rvq_mfma<<<nblocks, 512, 0, stream>>>(x, cb, cbS, cn, out, part);

    loss_kernel<<<1, 64, 0, stream>>>(part, out + (size_t)Bb * Dd * Tt);
}

// Round 7
// 418.606 us; speedup vs baseline: 12.2909x; 1.4074x over previous
//
#include <hip/hip_runtime.h>

// Problem constants
constexpr int Bb  = 16;
constexpr int Dd  = 128;
constexpr int Tt  = 2048;
constexpr int NQn = 8;
constexpr int CSc = 1024;

constexpr int TB   = 128;              // t per block
constexpr int CHC  = 32;               // codes per staged chunk
constexpr int NCHQ = 16;               // chunks per half per quantizer
constexpr int CHU  = CHC * Dd * 3;     // ushorts per chunk = 12288 (24 KB)

typedef __attribute__((ext_vector_type(8)))  short short8;
typedef __attribute__((ext_vector_type(4)))  float f32x4;
typedef __attribute__((ext_vector_type(16))) float f32x16;

// ---- bf16 helpers (RNE) ----
__device__ inline ushort f2bf(float f) {
    union { float f; unsigned u; } v; v.f = f;
    unsigned r = v.u + 0x7FFFu + ((v.u >> 16) & 1u);
    return (ushort)(r >> 16);
}
__device__ inline float bf2f(ushort h) {
    union { unsigned u; float f; } v; v.u = ((unsigned)h) << 16;
    return v.f;
}
__device__ inline void bsplit(float xv, ushort& h, ushort& m, ushort& l) {
    h = f2bf(xv);            float hf = bf2f(h);
    float r1 = xv - hf;      m = f2bf(r1);
    float mf = bf2f(m);      l = f2bf(r1 - mf);
}

// async global->LDS, 16 B/lane (LDS dest = wave-uniform base + lane*16)
__device__ inline void gload_lds16(const ushort* g, ushort* l) {
    __builtin_amdgcn_global_load_lds(
        (const __attribute__((address_space(1))) void*)g,
        (__attribute__((address_space(3))) void*)l, 16, 0, 0);
}

#define MFMA32(A, B, C) __builtin_amdgcn_mfma_f32_32x32x16_bf16(A, B, C, 0, 0, 0)

// ---------------------------------------------------------------------------
// Kernel 0: split codebook fp32 -> 3 bf16 planes, fragment-ordered per
// 32-code chunk for mfma_32x32x16: record (plane p, kstep ks, lane) holds
// code = chunk*32 + (lane&31), dims ks*16 + (lane>>5)*8 + j. Also ||c||^2.
// ---------------------------------------------------------------------------
__global__ __launch_bounds__(64) void split_kernel(const float* __restrict__ cb,
                                                   ushort* __restrict__ cbS,
                                                   float* __restrict__ cn) {
    const int c     = blockIdx.x * 64 + threadIdx.x;  // global code id
    const int chunk = c >> 5;
    const int c31   = c & 31;
    const float* p  = cb + (size_t)c * Dd;
    const size_t base = (size_t)chunk * CHU;

    float s0 = 0.f, s1 = 0.f, s2 = 0.f, s3 = 0.f;
#pragma unroll
    for (int ks = 0; ks < 8; ++ks) {
#pragma unroll
        for (int hi = 0; hi < 2; ++hi) {
            const int lanew = hi * 32 + c31;
            short8 h8, m8, l8;
#pragma unroll
            for (int jj = 0; jj < 8; jj += 4) {
                float4 v = *(const float4*)(p + ks * 16 + hi * 8 + jj);
                s0 = fmaf(v.x, v.x, s0);
                s1 = fmaf(v.y, v.y, s1);
                s2 = fmaf(v.z, v.z, s2);
                s3 = fmaf(v.w, v.w, s3);
                ushort hh, mm, ll;
                bsplit(v.x, hh, mm, ll); h8[jj+0] = (short)hh; m8[jj+0] = (short)mm; l8[jj+0] = (short)ll;
                bsplit(v.y, hh, mm, ll); h8[jj+1] = (short)hh; m8[jj+1] = (short)mm; l8[jj+1] = (short)ll;
                bsplit(v.z, hh, mm, ll); h8[jj+2] = (short)hh; m8[jj+2] = (short)mm; l8[jj+2] = (short)ll;
                bsplit(v.w, hh, mm, ll); h8[jj+3] = (short)hh; m8[jj+3] = (short)mm; l8[jj+3] = (short)ll;
            }
            *(short8*)&cbS[base + (size_t)((0 * 8 + ks) * 64 + lanew) * 8] = h8;
            *(short8*)&cbS[base + (size_t)((1 * 8 + ks) * 64 + lanew) * 8] = m8;
            *(short8*)&cbS[base + (size_t)((2 * 8 + ks) * 64 + lanew) * 8] = l8;
        }
    }
    cn[c] = (s0 + s1) + (s2 + s3);
}

// ---------------------------------------------------------------------------
// Kernel 1: MFMA RVQ. 512 threads = 8 waves = 4 t-tiles(32 t) x 2 code-halves.
// Residual lives ONLY as 3 bf16 split planes in registers (the MFMA
// B-fragments, 96 VGPR). Codebook chunks staged global->LDS double-buffered,
// each chunk read by the 4 t-tile waves of its half; 32x32x16 6-pass MFMA.
// ---------------------------------------------------------------------------
__global__ __launch_bounds__(512) void rvq_mfma(const float* __restrict__ x,
                                                const float* __restrict__ cb,
                                                const ushort* __restrict__ cbS,
                                                const float* __restrict__ cn_g,
                                                float* __restrict__ out,
                                                float* __restrict__ part) {
    __shared__ __align__(16) ushort sA[2][2][CHU];    // [half][dbuf] = 96 KB
    __shared__ __align__(16) float  cn_lds[CSc];      // 4 KB
    __shared__ float s_best[8][32];
    __shared__ int   s_idx[8][32];
    __shared__ float s_red[4];

    const int tid  = threadIdx.x;
    const int lane = tid & 63;
    const int w    = __builtin_amdgcn_readfirstlane(tid >> 6);
    const int tt   = w >> 1;          // t-tile 0..3
    const int h    = w & 1;           // code half
    const int l31  = lane & 31;       // t within tile / C-D column
    const int hi   = lane >> 5;       // k-subgroup 0..1

    const int t0  = blockIdx.x * TB;
    const int b   = t0 >> 11;
    const int tb0 = t0 & (Tt - 1);
    const int tg  = tb0 + tt * 32 + l31;
    const size_t xbase = (size_t)b * Dd * Tt;

    // ---- residual state: 3 bf16 planes, lane owns dims ks*16+hi*8+j of t=tg
    short8 Bf[3][8];
    float rn;
    {
        float p0 = 0.f, p1 = 0.f, p2 = 0.f, p3 = 0.f;
#pragma unroll
        for (int ks = 0; ks < 8; ++ks) {
            short8 h8, m8, l8;
#pragma unroll
            for (int j = 0; j < 8; ++j) {
                float v = x[xbase + (size_t)(ks * 16 + hi * 8 + j) * Tt + tg];
                ushort hh, mm, ll;
                bsplit(v, hh, mm, ll);
                h8[j] = (short)hh; m8[j] = (short)mm; l8[j] = (short)ll;
                if ((j & 3) == 0)      p0 = fmaf(v, v, p0);
                else if ((j & 3) == 1) p1 = fmaf(v, v, p1);
                else if ((j & 3) == 2) p2 = fmaf(v, v, p2);
                else                   p3 = fmaf(v, v, p3);
            }
            Bf[0][ks] = h8; Bf[1][ks] = m8; Bf[2][ks] = l8;
        }
        float rnp = (p0 + p1) + (p2 + p3);
        rnp += __shfl_xor(rnp, 32, 64);   // pair lanes share t
        rn = rnp;
    }

    float loss_acc = 0.f;

#pragma unroll 1
    for (int q = 0; q < NQn; ++q) {
        // stage ||c||^2 for this quantizer
        *(float2*)&cn_lds[tid * 2] = *(const float2*)&cn_g[(size_t)q * CSc + tid * 2];

        // cooperative chunk staging: wave w stages 6 KB of the 48 KB pair
        auto STAGE = [&](int ct, int bb) {
            const int hh = w >> 2, sl = w & 3;
            const int gc = q * 32 + hh * 16 + ct;
            const ushort* g = cbS + (size_t)gc * CHU + sl * 3072 + lane * 8;
            ushort* dl = &sA[hh][bb][sl * 3072];
#pragma unroll
            for (int i = 0; i < 6; ++i) gload_lds16(g + i * 512, dl + i * 512);
        };

        STAGE(0, 0);
        asm volatile("s_waitcnt vmcnt(0)" ::: "memory");
        __syncthreads();

        float best = 3.4e38f;
        int   bidx = 0;

#pragma unroll 1
        for (int ct = 0; ct < NCHQ; ++ct) {
            const int bb = ct & 1;
            if (ct + 1 < NCHQ) STAGE(ct + 1, bb ^ 1);

            const ushort* ab = &sA[h][bb][0];
            f32x16 accA = {0.f,0.f,0.f,0.f,0.f,0.f,0.f,0.f,0.f,0.f,0.f,0.f,0.f,0.f,0.f,0.f};
            f32x16 accB = {0.f,0.f,0.f,0.f,0.f,0.f,0.f,0.f,0.f,0.f,0.f,0.f,0.f,0.f,0.f,0.f};

            __builtin_amdgcn_s_setprio(1);
#pragma unroll
            for (int ks = 0; ks < 8; ++ks) {
                short8 Ah = *(const short8*)&ab[(size_t)((0 * 8 + ks) * 64 + lane) * 8];
                short8 Am = *(const short8*)&ab[(size_t)((1 * 8 + ks) * 64 + lane) * 8];
                short8 Al = *(const short8*)&ab[(size_t)((2 * 8 + ks) * 64 + lane) * 8];
                accA = MFMA32(Ah, Bf[0][ks], accA);   // HH
                accB = MFMA32(Am, Bf[1][ks], accB);   // MM
                accA = MFMA32(Ah, Bf[1][ks], accA);   // H M_r
                accB = MFMA32(Ah, Bf[2][ks], accB);   // H L_r
                accA = MFMA32(Am, Bf[0][ks], accA);   // M H_r
                accB = MFMA32(Al, Bf[0][ks], accB);   // L H_r
            }
            __builtin_amdgcn_s_setprio(0);

            f32x16 accT = accA + accB;
            const int cq = h * 512 + ct * 32;
#pragma unroll
            for (int blk = 0; blk < 4; ++blk) {
                f32x4 cn4 = *(const f32x4*)&cn_lds[cq + blk * 8 + hi * 4];
#pragma unroll
                for (int e = 0; e < 4; ++e) {
                    // C/D: row(code) = (reg&3) + 8*(reg>>2) + 4*hi, reg = blk*4+e
                    float dd = fmaf(-2.f, accT[blk * 4 + e], rn + cn4[e]);
                    int cid = cq + blk * 8 + hi * 4 + e;   // ascending per lane
                    if (dd < best) { best = dd; bidx = cid; }  // strict <
                }
            }

            asm volatile("s_waitcnt vmcnt(0)" ::: "memory");
            __syncthreads();
        }

        // ---- argmin: combine the two k-subgroups (same t), lexicographic ----
        {
            float ob = __shfl_xor(best, 32, 64);
            int   oi = __shfl_xor(bidx, 32, 64);
            if (ob < best || (ob == best && oi < bidx)) { best = ob; bidx = oi; }
        }
        if (hi == 0) { s_best[w][l31] = best; s_idx[w][l31] = bidx; }
        __syncthreads();
        // combine with partner half (lex -> lowest index wins ties)
        {
            float ob = s_best[w ^ 1][l31];
            int   oi = s_idx[w ^ 1][l31];
            if (ob < best || (ob == best && oi < bidx)) { best = ob; bidx = oi; }
        }
        const int g = bidx;

        // ---- residual update: reconstruct H+M+L, subtract fp32 code, re-split
        {
            const float* cp = cb + ((size_t)q * CSc + g) * Dd + hi * 8;
            float q0 = 0.f, q1 = 0.f, q2 = 0.f, q3 = 0.f;
#pragma unroll
            for (int ks = 0; ks < 8; ++ks) {
                short8 h8 = Bf[0][ks], m8 = Bf[1][ks], l8 = Bf[2][ks];
                float4 ca  = *(const float4*)(cp + ks * 16);
                float4 cb4 = *(const float4*)(cp + ks * 16 + 4);
                float nv0 = ((bf2f((ushort)h8[0]) + bf2f((ushort)m8[0])) + bf2f((ushort)l8[0])) - ca.x;
                float nv1 = ((bf2f((ushort)h8[1]) + bf2f((ushort)m8[1])) + bf2f((ushort)l8[1])) - ca.y;
                float nv2 = ((bf2f((ushort)h8[2]) + bf2f((ushort)m8[2])) + bf2f((ushort)l8[2])) - ca.z;
                float nv3 = ((bf2f((ushort)h8[3]) + bf2f((ushort)m8[3])) + bf2f((ushort)l8[3])) - ca.w;
                float nv4 = ((bf2f((ushort)h8[4]) + bf2f((ushort)m8[4])) + bf2f((ushort)l8[4])) - cb4.x;
                float nv5 = ((bf2f((ushort)h8[5]) + bf2f((ushort)m8[5])) + bf2f((ushort)l8[5])) - cb4.y;
                float nv6 = ((bf2f((ushort)h8[6]) + bf2f((ushort)m8[6])) + bf2f((ushort)l8[6])) - cb4.z;
                float nv7 = ((bf2f((ushort)h8[7]) + bf2f((ushort)m8[7])) + bf2f((ushort)l8[7])) - cb4.w;
                q0 = fmaf(nv0, nv0, q0); q1 = fmaf(nv1, nv1, q1);
                q2 = fmaf(nv2, nv2, q2); q3 = fmaf(nv3, nv3, q3);
                q0 = fmaf(nv4, nv4, q0); q1 = fmaf(nv5, nv5, q1);
                q2 = fmaf(nv6, nv6, q2); q3 = fmaf(nv7, nv7, q3);
                short8 nh, nm, nl;
                ushort hh, mm, ll;
                bsplit(nv0, hh, mm, ll); nh[0] = (short)hh; nm[0] = (short)mm; nl[0] = (short)ll;
                bsplit(nv1, hh, mm, ll); nh[1] = (short)hh; nm[1] = (short)mm; nl[1] = (short)ll;
                bsplit(nv2, hh, mm, ll); nh[2] = (short)hh; nm[2] = (short)mm; nl[2] = (short)ll;
                bsplit(nv3, hh, mm, ll); nh[3] = (short)hh; nm[3] = (short)mm; nl[3] = (short)ll;
                bsplit(nv4, hh, mm, ll); nh[4] = (short)hh; nm[4] = (short)mm; nl[4] = (short)ll;
                bsplit(nv5, hh, mm, ll); nh[5] = (short)hh; nm[5] = (short)mm; nl[5] = (short)ll;
                bsplit(nv6, hh, mm, ll); nh[6] = (short)hh; nm[6] = (short)mm; nl[6] = (short)ll;
                bsplit(nv7, hh, mm, ll); nh[7] = (short)hh; nm[7] = (short)mm; nl[7] = (short)ll;
                Bf[0][ks] = nh; Bf[1][ks] = nm; Bf[2][ks] = nl;
            }
            float rnn = (q0 + q1) + (q2 + q3);
            rnn += __shfl_xor(rnn, 32, 64);
            rn = rnn;                       // ||r||^2 for next stage
            if (h == 0) loss_acc += rnn;    // counted by both hi lanes -> x2
        }
    }

    // ---- epilogue: q_sum = x0 - r_final (h==0 waves; state identical) ----
    if (h == 0) {
#pragma unroll
        for (int ks = 0; ks < 8; ++ks) {
            short8 h8 = Bf[0][ks], m8 = Bf[1][ks], l8 = Bf[2][ks];
#pragma unroll
            for (int j = 0; j < 8; ++j) {
                size_t off = xbase + (size_t)(ks * 16 + hi * 8 + j) * Tt + tg;
                out[off] = x[off] -
                    ((bf2f((ushort)h8[j]) + bf2f((ushort)m8[j])) + bf2f((ushort)l8[j]));
            }
        }
        float ls = loss_acc;
#pragma unroll
        for (int off = 32; off > 0; off >>= 1) ls += __shfl_down(ls, off, 64);
        if (lane == 0) s_red[tt] = ls;
    }
    __syncthreads();
    if (tid == 0)
        part[blockIdx.x] = 0.5f * ((s_red[0] + s_red[1]) + (s_red[2] + s_red[3]));
}

// ---------------------------------------------------------------------------
// Kernel 2: deterministic loss reduction (16 block-partials per batch element)
// ---------------------------------------------------------------------------
__global__ __launch_bounds__(64) void loss_kernel(const float* __restrict__ part,
                                                  float* __restrict__ out_loss) {
    int b = threadIdx.x;
    if (b < Bb) {
        float s = 0.f;
        const int ppb = Tt / TB;  // 16
        for (int k = 0; k < ppb; ++k) s += part[b * ppb + k];
        out_loss[b] = s * (1.0f / ((float)Dd * (float)Tt));
    }
}

// ---------------------------------------------------------------------------
extern "C" void kernel_launch(void* const* d_in, const int* in_sizes, int n_in,
                              void* d_out, int out_size, void* d_ws, size_t ws_size,
                              hipStream_t stream) {
    const float* x  = (const float*)d_in[0];   // [B, D, T]
    const float* cb = (const float*)d_in[1];   // [NQ, CS, D]
    float* out = (float*)d_out;                // [B*D*T] q_sum ++ [B] loss_sum

    // workspace: cn[8192] f32 | part[256] f32 | cbS fragment-ordered (6.3 MB)
    float*  cn   = (float*)d_ws;
    float*  part = cn + NQn * CSc;
    ushort* cbS  = (ushort*)(part + 256);

    split_kernel<<<(NQn * CSc) / 64, 64, 0, stream>>>(cb, cbS, cn);

    const int nblocks = (Bb * Tt) / TB;  // 256
    rvq_mfma<<<nblocks, 512, 0, stream>>>(x, cb, cbS, cn, out, part);

    loss_kernel<<<1, 64, 0, stream>>>(part, out + (size_t)Bb * Dd * Tt);
}